// Round 8
// baseline (161.126 us; speedup 1.0000x reference)
//
#include <hip/hip_runtime.h>

// Problem constants (match reference setup_inputs)
#define BB 4
#define NN 10000
#define FF 128
#define UU 128
#define EE 160000

typedef __bf16 bf16x8 __attribute__((ext_vector_type(8)));
typedef float  f32x4  __attribute__((ext_vector_type(4)));
typedef float  f32x2  __attribute__((ext_vector_type(2)));

// ws layout (bytes)
#define WS_S      0         // float S (4 B)
#define WS_DONE   4         // int done-counter (zeroed with S/deg)
#define WS_DEG    256       // int[10000]
#define WS_OFFS   40448     // int[10001]
#define WS_CUR    80640     // int[10000]
#define WS_TGT    120832    // int[160000]            (CSR-ordered tgt)
#define WS_EXW    760832    // float4[160000]         (CSR-ordered weights)
#define WS_P      3320832   // float[40000]  p2[n][b] (node-major float4)
#define WS_Q      3480832   // float[40000]  q2[n][b]
#define WS_BTG    3640832   // bf16 swizzled W_t (32 KB)
#define WS_BCG    3673600   // bf16 swizzled W_c (64 KB, K-half row-remapped)
#define WS_HS     3739136   // bf16 hs2[10000][4][256] (h | scat interleaved)
#define WS_H8     24219136  // fp8  h8[10000][4][128]  (gather copy; chunk byte c = col 16c+lr)

// ---------------------------------------------------------------------------
// k_prep: zero S+done+deg; pre-swizzle W_t and W_c into bf16 MFMA-frag layout.
// W_c K-half (k'>=128) uses the sigma remap: frag position t=k'-128=(sub*8+c)
// sources Wc row 128 + 16*c + sub, matching h8/scat's permuted column order.
__global__ __launch_bounds__(256) void k_prep(const float* __restrict__ Wt,
                                              const float* __restrict__ Wc,
                                              char* __restrict__ ws) {
  const int gid = blockIdx.x * 256 + threadIdx.x;  // 8 blocks -> 2048 threads
  uint4* zp = (uint4*)ws;
  uint4 z = {0u, 0u, 0u, 0u};
  for (int i = gid; i < 2528; i += 2048) zp[i] = z;

  __bf16* Btg = (__bf16*)(ws + WS_BTG);
  __bf16* Bcg = (__bf16*)(ws + WS_BCG);
  {
    int i = gid;
    int n = i & 127, kb8 = i >> 7;  // kb8 in [0,16)
    int kc = kb8 >> 2, kbq = kb8 & 3;
    int lane = (n & 15) | (kbq << 4), c = n >> 4;
    const float* src = Wt + (size_t)kb8 * 8 * 128 + n;
    bf16x8 v;
#pragma unroll
    for (int j = 0; j < 8; ++j) v[j] = (__bf16)src[(size_t)j * 128];
    *(bf16x8*)(Btg + ((kc * 8 + c) * 512 + lane * 8)) = v;
  }
#pragma unroll
  for (int it = 0; it < 2; ++it) {
    int i = gid + it * 2048;
    int n = i & 127, kb8 = i >> 7;  // kb8 in [0,32)
    int kc = kb8 >> 2, kbq = kb8 & 3;
    int lane = (n & 15) | (kbq << 4), c = n >> 4;
    bf16x8 v;
    if (kb8 < 16) {  // K-low half: natural rows
      const float* src = Wc + (size_t)kb8 * 8 * 128 + n;
#pragma unroll
      for (int j = 0; j < 8; ++j) v[j] = (__bf16)src[(size_t)j * 128];
    } else {  // K-high half: sigma remap (sub = kb8-16, c = j -> row 128+16j+sub)
      int sub = kb8 - 16;
      const float* src = Wc + (size_t)(128 + sub) * 128 + n;
#pragma unroll
      for (int j = 0; j < 8; ++j) v[j] = (__bf16)src[(size_t)j * 16 * 128];
    }
    *(bf16x8*)(Bcg + ((kc * 8 + c) * 512 + lane * 8)) = v;
  }
}

// ---------------------------------------------------------------------------
// GEMM1: h = relu(nf @ W_t + b_t) -> hs2 (bf16) + h8 (fp8 chunk layout);
// fused p2/q2, degree count, AND the CSR scan (last-block pattern: the final
// block to finish its deg atomics runs the 10000-elem exclusive scan while
// the other 312 blocks proceed with MFMA). 313 blocks x 512 threads.
__global__ __launch_bounds__(512) void k_gemm_h(
    const float* __restrict__ nf, const __bf16* __restrict__ Btg,
    const float* __restrict__ bt, const float* __restrict__ Wa,
    const int* __restrict__ eidx, int* __restrict__ deg,
    int* __restrict__ done, int* __restrict__ offs, int* __restrict__ cursor,
    __bf16* __restrict__ hs, char* __restrict__ h8,
    float* __restrict__ p2, float* __restrict__ q2) {
  {
    int e = blockIdx.x * 512 + threadIdx.x;
    if (e < EE) atomicAdd(&deg[eidx[2 * e]], 1);
  }
  __syncthreads();  // drains vmcnt -> this block's deg atomics are complete
  __shared__ int lastflag;
  if (threadIdx.x == 0) {
    __threadfence();
    int prev = atomicAdd(done, 1);
    lastflag = (prev == (int)gridDim.x - 1) ? 1 : 0;
  }
  __syncthreads();
  if (lastflag) {  // block-uniform branch: fused exclusive scan
    const int t = threadIdx.x, lane = t & 63, wv = t >> 6;  // 8 waves
    const int base = t * 20;
    int local[20];
    int s = 0;
#pragma unroll
    for (int i = 0; i < 20; ++i) {
      int idx = base + i;
      int v = (idx < NN) ? atomicAdd(&deg[idx], 0) : 0;  // device-scope read
      local[i] = s;
      s += v;
    }
    const int tsum = s;
#pragma unroll
    for (int off = 1; off < 64; off <<= 1) {
      int v = __shfl_up(s, off);
      if (lane >= off) s += v;
    }
    __shared__ int wsum[8];
    if (lane == 63) wsum[wv] = s;
    __syncthreads();
    int add = 0;
#pragma unroll
    for (int w = 0; w < 8; ++w) {
      int v = wsum[w];
      if (w < wv) add += v;
    }
    int pre = add + s - tsum;
#pragma unroll
    for (int i = 0; i < 20; ++i) {
      int idx = base + i;
      if (idx < NN) {
        int o = pre + local[i];
        offs[idx] = o;
        cursor[idx] = o;
      }
    }
    if (t == 511) offs[NN] = pre + tsum;  // == EE
    __syncthreads();  // uniform: pair with the non-last path below
  } else {
    __syncthreads();  // keep barrier counts identical on both paths
  }

  __shared__ __bf16 Bt[32 * 512];  // 32 KB
  const int tid = threadIdx.x;
  {
    uint4* d = (uint4*)Bt;
    const uint4* s = (const uint4*)Btg;
#pragma unroll
    for (int i = tid; i < 2048; i += 512) d[i] = s[i];
  }
  __syncthreads();

  const int wid = tid >> 6, lane = tid & 63;
  const int lr = lane & 15, lg = lane >> 4;
  const int row0 = blockIdx.x * 128 + wid * 16;

  f32x4 acc[8];
#pragma unroll
  for (int c = 0; c < 8; ++c)
#pragma unroll
    for (int r = 0; r < 4; ++r) acc[c][r] = 0.f;

  const int arow = min(row0 + lr, 39999);  // tail clamp (loads only)

#pragma unroll
  for (int k0 = 0; k0 < 128; k0 += 32) {
    int kk = k0 + lg * 8;
    const float4* ap = (const float4*)(nf + (size_t)arow * 128 + kk);
    float4 a0 = ap[0], a1 = ap[1];
    bf16x8 af;
    af[0] = (__bf16)a0.x; af[1] = (__bf16)a0.y; af[2] = (__bf16)a0.z; af[3] = (__bf16)a0.w;
    af[4] = (__bf16)a1.x; af[5] = (__bf16)a1.y; af[6] = (__bf16)a1.z; af[7] = (__bf16)a1.w;
#pragma unroll
    for (int c = 0; c < 8; ++c) {
      bf16x8 bf = *(const bf16x8*)(Bt + (((k0 >> 5) << 3) + c) * 512 + lane * 8);
      acc[c] = __builtin_amdgcn_mfma_f32_16x16x32_bf16(af, bf, acc[c], 0, 0, 0);
    }
  }

#pragma unroll
  for (int r = 0; r < 4; ++r) {
    int row = row0 + lg * 4 + r;  // m = b*NN + n
    bool ok = row < 40000;
    int b = row / NN;
    int n = row - b * NN;
    size_t dst = ((size_t)n * 4 + b) * 256;  // hs2 row
    float vv[8];
    float pr = 0.f, qr = 0.f;
#pragma unroll
    for (int c = 0; c < 8; ++c) {
      int col = c * 16 + lr;
      float v = acc[c][r] + bt[col];
      v = fmaxf(v, 0.f);
      vv[c] = v;
      if (ok) hs[dst + col] = (__bf16)v;
      pr += v * Wa[col];
      qr += v * Wa[128 + col];
    }
    // fp8 chunk: byte c = col 16c+lr
    int d0 = __builtin_amdgcn_cvt_pk_fp8_f32(vv[0], vv[1], 0, false);
    d0 = __builtin_amdgcn_cvt_pk_fp8_f32(vv[2], vv[3], d0, true);
    int d1 = __builtin_amdgcn_cvt_pk_fp8_f32(vv[4], vv[5], 0, false);
    d1 = __builtin_amdgcn_cvt_pk_fp8_f32(vv[6], vv[7], d1, true);
    if (ok) {
      uint2 st = make_uint2((unsigned)d0, (unsigned)d1);
      *(uint2*)(h8 + ((size_t)n * 4 + b) * 128 + lr * 8) = st;
    }
#pragma unroll
    for (int m = 1; m < 16; m <<= 1) {
      pr += __shfl_xor(pr, m);
      qr += __shfl_xor(qr, m);
    }
    if (lr == 0 && ok) {
      p2[n * 4 + b] = pr;
      q2[n * 4 + b] = qr;
    }
  }
}

// ---------------------------------------------------------------------------
// k_att: one thread per EDGE. All 4 batches' exp(tanh(...)); claims the CSR
// slot; ONE float4 store (exw) + one int store (tgt); accumulates S.
__global__ __launch_bounds__(256) void k_att(const int* __restrict__ eidx,
                                             const float4* __restrict__ p2,
                                             const float4* __restrict__ q2,
                                             const float* __restrict__ ba,
                                             int* __restrict__ cursor,
                                             int* __restrict__ tgts,
                                             float4* __restrict__ exw,
                                             float* __restrict__ S) {
  int e = blockIdx.x * 256 + threadIdx.x;  // < 160000 exactly
  int s = eidx[2 * e], t = eidx[2 * e + 1];
  float4 pv = p2[s];
  float4 qv = q2[t];
  float bias = ba[0];
#define ATT(pc, qc, out)                              \
  {                                                   \
    float a = (pc) + (qc) + bias;                     \
    float z = __expf(2.f * a);                        \
    float th = 1.f - __fdividef(2.f, z + 1.f);        \
    (out) = __expf(th);                               \
  }
  float v0, v1, v2, v3;
  ATT(pv.x, qv.x, v0)
  ATT(pv.y, qv.y, v1)
  ATT(pv.z, qv.z, v2)
  ATT(pv.w, qv.w, v3)
#undef ATT
  int pos = atomicAdd(&cursor[s], 1);
  tgts[pos] = t;
  exw[pos] = make_float4(v0, v1, v2, v3);
  float vs = v0 + v1 + v2 + v3;
#pragma unroll
  for (int m = 1; m < 64; m <<= 1) vs += __shfl_xor(vs, m);
  __shared__ float part[4];
  int wid = threadIdx.x >> 6, lane = threadIdx.x & 63;
  if (lane == 0) part[wid] = vs;
  __syncthreads();
  if (threadIdx.x == 0) atomicAdd(S, part[0] + part[1] + part[2] + part[3]);
}

// ---------------------------------------------------------------------------
// k_agg: one wave per node. Per edge: ONE 8 B load/lane from the fp8 h copy
// covers all 4 batches (lane = batch myb, chunk sub). acc[c] <-> col 16c+sub;
// the scat-store position sub*8+c is compensated by k_prep's Bcg row remap.
__global__ __launch_bounds__(256) void k_agg(
    const int* __restrict__ tgts, const int* __restrict__ offs,
    const float4* __restrict__ exw, const float* __restrict__ S,
    const char* __restrict__ h8, __bf16* __restrict__ hs) {
  const int wid = threadIdx.x >> 6, lane = threadIdx.x & 63;
  const int n = blockIdx.x * 4 + wid;  // < 10000 exactly (2500 blocks)
  const int myb = lane >> 4, sub = lane & 15;
  const int o0 = offs[n], o1 = offs[n + 1];
  const uint2* __restrict__ h8u = (const uint2*)h8;  // 64 uint2 per node
  float acc[8];
#pragma unroll
  for (int i = 0; i < 8; ++i) acc[i] = 0.f;

  const int lslot = myb * 16 + sub;  // lane's uint2 slot within a node block
  const int wsrc = myb << 4;
  for (int base = o0; base < o1; base += 16) {
    int idx = base + sub;
    bool valid = idx < o1;
    int t_l = valid ? tgts[idx] : 0;
    float4 w4 = valid ? exw[idx] : make_float4(0.f, 0.f, 0.f, 0.f);
    float w_l = (myb == 0) ? w4.x : (myb == 1) ? w4.y : (myb == 2) ? w4.z : w4.w;
    int cnt = min(16, o1 - base);
    for (int j = 0; j < cnt; j += 4) {
      int t0 = __shfl(t_l, j + 0);
      int t1 = __shfl(t_l, j + 1);
      int t2 = __shfl(t_l, j + 2);
      int t3 = __shfl(t_l, j + 3);
      float m0 = __shfl(w_l, wsrc | (j + 0));
      float m1 = __shfl(w_l, wsrc | (j + 1));
      float m2 = __shfl(w_l, wsrc | (j + 2));
      float m3 = __shfl(w_l, wsrc | (j + 3));
      uint2 va = h8u[(size_t)t0 * 64 + lslot];
      uint2 vb = h8u[(size_t)t1 * 64 + lslot];
      uint2 vc = h8u[(size_t)t2 * 64 + lslot];
      uint2 vd = h8u[(size_t)t3 * 64 + lslot];
#define ACC8(m, v)                                                        \
  {                                                                       \
    f32x2 f01 = __builtin_amdgcn_cvt_pk_f32_fp8((int)(v).x, false);       \
    f32x2 f23 = __builtin_amdgcn_cvt_pk_f32_fp8((int)(v).x, true);        \
    f32x2 f45 = __builtin_amdgcn_cvt_pk_f32_fp8((int)(v).y, false);       \
    f32x2 f67 = __builtin_amdgcn_cvt_pk_f32_fp8((int)(v).y, true);        \
    acc[0] = fmaf((m), f01.x, acc[0]); acc[1] = fmaf((m), f01.y, acc[1]); \
    acc[2] = fmaf((m), f23.x, acc[2]); acc[3] = fmaf((m), f23.y, acc[3]); \
    acc[4] = fmaf((m), f45.x, acc[4]); acc[5] = fmaf((m), f45.y, acc[5]); \
    acc[6] = fmaf((m), f67.x, acc[6]); acc[7] = fmaf((m), f67.y, acc[7]); \
  }
      ACC8(m0, va)
      ACC8(m1, vb)
      ACC8(m2, vc)
      ACC8(m3, vd)
#undef ACC8
    }
  }
  const float invS = 1.0f / S[0];
  uint4 st;
  unsigned* sp = (unsigned*)&st;
#pragma unroll
  for (int i = 0; i < 4; ++i) {
    unsigned ux = __float_as_uint(acc[2 * i] * invS);
    ux = (ux + 0x7fffu + ((ux >> 16) & 1u)) >> 16;
    unsigned uy = __float_as_uint(acc[2 * i + 1] * invS);
    uy = (uy + 0x7fffu + ((uy >> 16) & 1u)) >> 16;
    sp[i] = ux | (uy << 16);
  }
  ((uint4*)hs)[(size_t)n * 128 + myb * 32 + 16 + sub] = st;  // scat half
}

// ---------------------------------------------------------------------------
// GEMM2: out = relu(hs2 @ W_c + b_c)  (M=40000 rows m=n*4+b, K=256, N=128)
// 313 blocks x 512 threads; Bcg's K-half row remap matches scat's layout.
__global__ __launch_bounds__(512) void k_gemm_out(
    const __bf16* __restrict__ hs, const __bf16* __restrict__ Bcg,
    const float* __restrict__ bc, float* __restrict__ out) {
  __shared__ __bf16 Bt[64 * 512];  // 64 KB
  const int tid = threadIdx.x;
  {
    uint4* d = (uint4*)Bt;
    const uint4* s = (const uint4*)Bcg;
#pragma unroll
    for (int i = tid; i < 4096; i += 512) d[i] = s[i];
  }
  __syncthreads();

  const int wid = tid >> 6, lane = tid & 63;
  const int lr = lane & 15, lg = lane >> 4;
  const int row0 = blockIdx.x * 128 + wid * 16;

  f32x4 acc[8];
#pragma unroll
  for (int c = 0; c < 8; ++c)
#pragma unroll
    for (int r = 0; r < 4; ++r) acc[c][r] = 0.f;

  const int arow = min(row0 + lr, 39999);  // tail clamp (loads only)

#pragma unroll
  for (int k0 = 0; k0 < 256; k0 += 32) {
    int kk = k0 + lg * 8;
    bf16x8 af = *(const bf16x8*)(hs + (size_t)arow * 256 + kk);
#pragma unroll
    for (int c = 0; c < 8; ++c) {
      bf16x8 bf = *(const bf16x8*)(Bt + (((k0 >> 5) << 3) + c) * 512 + lane * 8);
      acc[c] = __builtin_amdgcn_mfma_f32_16x16x32_bf16(af, bf, acc[c], 0, 0, 0);
    }
  }

#pragma unroll
  for (int r = 0; r < 4; ++r) {
    int m = row0 + lg * 4 + r;  // hs2 row = n*4+b
    if (m < 40000) {
      int n = m >> 2, b = m & 3;
      size_t orow = ((size_t)b * NN + n) * 128;
#pragma unroll
      for (int c = 0; c < 8; ++c) {
        int col = c * 16 + lr;
        float v = acc[c][r] + bc[col];
        out[orow + col] = fmaxf(v, 0.f);
      }
    }
  }
}

// ---------------------------------------------------------------------------
extern "C" void kernel_launch(void* const* d_in, const int* in_sizes, int n_in,
                              void* d_out, int out_size, void* d_ws,
                              size_t ws_size, hipStream_t stream) {
  const float* nf = (const float*)d_in[0];
  const int* eidx = (const int*)d_in[1];
  const float* Wt = (const float*)d_in[2];
  const float* bt = (const float*)d_in[3];
  const float* Wa = (const float*)d_in[4];
  const float* ba = (const float*)d_in[5];
  const float* Wc = (const float*)d_in[6];
  const float* bc = (const float*)d_in[7];
  float* out = (float*)d_out;

  char* w = (char*)d_ws;
  float* S = (float*)(w + WS_S);
  int* done = (int*)(w + WS_DONE);
  int* deg = (int*)(w + WS_DEG);
  int* offs = (int*)(w + WS_OFFS);
  int* cursor = (int*)(w + WS_CUR);
  int* tgts = (int*)(w + WS_TGT);
  float4* exw = (float4*)(w + WS_EXW);
  float* p2 = (float*)(w + WS_P);
  float* q2 = (float*)(w + WS_Q);
  __bf16* Btg = (__bf16*)(w + WS_BTG);
  __bf16* Bcg = (__bf16*)(w + WS_BCG);
  __bf16* hs = (__bf16*)(w + WS_HS);
  char* h8 = w + WS_H8;

  k_prep<<<8, 256, 0, stream>>>(Wt, Wc, w);
  k_gemm_h<<<313, 512, 0, stream>>>(nf, Btg, bt, Wa, eidx, deg, done, offs,
                                    cursor, hs, h8, p2, q2);
  k_att<<<625, 256, 0, stream>>>(eidx, (const float4*)p2, (const float4*)q2,
                                 ba, cursor, tgts, exw, S);
  k_agg<<<2500, 256, 0, stream>>>(tgts, offs, exw, S, h8, hs);
  k_gemm_out<<<313, 512, 0, stream>>>(hs, Bcg, bc, out);
}

// Round 9
// 154.607 us; speedup vs baseline: 1.0422x; 1.0422x over previous
//
#include <hip/hip_runtime.h>

// Problem constants (match reference setup_inputs)
#define BB 4
#define NN 10000
#define FF 128
#define UU 128
#define EE 160000

typedef __bf16 bf16x8 __attribute__((ext_vector_type(8)));
typedef float  f32x4  __attribute__((ext_vector_type(4)));
typedef float  f32x2  __attribute__((ext_vector_type(2)));

// ws layout (bytes)
#define WS_S      0         // float S (4 B)
#define WS_DEG    256       // int[10000]
#define WS_OFFS   40448     // int[10001]
#define WS_CUR    80640     // int[10000]
#define WS_TGT    120832    // int[160000]            (CSR-ordered tgt)
#define WS_EXW    760832    // float4[160000]         (CSR-ordered weights)
#define WS_P      3320832   // float[40000]  p2[n][b] (node-major float4)
#define WS_Q      3480832   // float[40000]  q2[n][b]
#define WS_BTG    3640832   // bf16 swizzled W_t (32 KB)
#define WS_BCG    3673600   // bf16 swizzled W_c (64 KB, K-half row-remapped)
#define WS_HS     3739136   // bf16 hs2[10000][4][256] (h | scat interleaved)
#define WS_H8     24219136  // fp8  h8[10000][4][128]  (gather copy; chunk byte c = col 16c+lr)

// ---------------------------------------------------------------------------
// k_prep: zero S+deg; pre-swizzle W_t and W_c into bf16 MFMA-frag layout.
// W_c K-half (k'>=128) uses the sigma remap: frag position t=k'-128=(sub*8+c)
// sources Wc row 128 + 16*c + sub, matching h8/scat's permuted column order.
__global__ __launch_bounds__(256) void k_prep(const float* __restrict__ Wt,
                                              const float* __restrict__ Wc,
                                              char* __restrict__ ws) {
  const int gid = blockIdx.x * 256 + threadIdx.x;  // 8 blocks -> 2048 threads
  uint4* zp = (uint4*)ws;
  uint4 z = {0u, 0u, 0u, 0u};
  for (int i = gid; i < 2528; i += 2048) zp[i] = z;

  __bf16* Btg = (__bf16*)(ws + WS_BTG);
  __bf16* Bcg = (__bf16*)(ws + WS_BCG);
  {
    int i = gid;
    int n = i & 127, kb8 = i >> 7;  // kb8 in [0,16)
    int kc = kb8 >> 2, kbq = kb8 & 3;
    int lane = (n & 15) | (kbq << 4), c = n >> 4;
    const float* src = Wt + (size_t)kb8 * 8 * 128 + n;
    bf16x8 v;
#pragma unroll
    for (int j = 0; j < 8; ++j) v[j] = (__bf16)src[(size_t)j * 128];
    *(bf16x8*)(Btg + ((kc * 8 + c) * 512 + lane * 8)) = v;
  }
#pragma unroll
  for (int it = 0; it < 2; ++it) {
    int i = gid + it * 2048;
    int n = i & 127, kb8 = i >> 7;  // kb8 in [0,32)
    int kc = kb8 >> 2, kbq = kb8 & 3;
    int lane = (n & 15) | (kbq << 4), c = n >> 4;
    bf16x8 v;
    if (kb8 < 16) {  // K-low half: natural rows
      const float* src = Wc + (size_t)kb8 * 8 * 128 + n;
#pragma unroll
      for (int j = 0; j < 8; ++j) v[j] = (__bf16)src[(size_t)j * 128];
    } else {  // K-high half: sigma remap (sub = kb8-16, c = j -> row 128+16j+sub)
      int sub = kb8 - 16;
      const float* src = Wc + (size_t)(128 + sub) * 128 + n;
#pragma unroll
      for (int j = 0; j < 8; ++j) v[j] = (__bf16)src[(size_t)j * 16 * 128];
    }
    *(bf16x8*)(Bcg + ((kc * 8 + c) * 512 + lane * 8)) = v;
  }
}

// ---------------------------------------------------------------------------
// GEMM1: h = relu(nf @ W_t + b_t) -> hs2 (bf16) + h8 (fp8 chunk layout);
// fused p2/q2 and degree count. 313 blocks x 512 threads, 16 rows/wave
// (R6 shape: low VGPR, compiler interleaves A-loads with MFMA).
__global__ __launch_bounds__(512) void k_gemm_h(
    const float* __restrict__ nf, const __bf16* __restrict__ Btg,
    const float* __restrict__ bt, const float* __restrict__ Wa,
    const int* __restrict__ eidx, int* __restrict__ deg,
    __bf16* __restrict__ hs, char* __restrict__ h8,
    float* __restrict__ p2, float* __restrict__ q2) {
  {
    int e = blockIdx.x * 512 + threadIdx.x;
    if (e < EE) atomicAdd(&deg[eidx[2 * e]], 1);
  }
  __shared__ __bf16 Bt[32 * 512];  // 32 KB
  const int tid = threadIdx.x;
  {
    uint4* d = (uint4*)Bt;
    const uint4* s = (const uint4*)Btg;
#pragma unroll
    for (int i = tid; i < 2048; i += 512) d[i] = s[i];
  }
  __syncthreads();

  const int wid = tid >> 6, lane = tid & 63;
  const int lr = lane & 15, lg = lane >> 4;
  const int row0 = blockIdx.x * 128 + wid * 16;

  f32x4 acc[8];
#pragma unroll
  for (int c = 0; c < 8; ++c)
#pragma unroll
    for (int r = 0; r < 4; ++r) acc[c][r] = 0.f;

  const int arow = min(row0 + lr, 39999);  // tail clamp (loads only)

#pragma unroll
  for (int k0 = 0; k0 < 128; k0 += 32) {
    int kk = k0 + lg * 8;
    const float4* ap = (const float4*)(nf + (size_t)arow * 128 + kk);
    float4 a0 = ap[0], a1 = ap[1];
    bf16x8 af;
    af[0] = (__bf16)a0.x; af[1] = (__bf16)a0.y; af[2] = (__bf16)a0.z; af[3] = (__bf16)a0.w;
    af[4] = (__bf16)a1.x; af[5] = (__bf16)a1.y; af[6] = (__bf16)a1.z; af[7] = (__bf16)a1.w;
#pragma unroll
    for (int c = 0; c < 8; ++c) {
      bf16x8 bf = *(const bf16x8*)(Bt + (((k0 >> 5) << 3) + c) * 512 + lane * 8);
      acc[c] = __builtin_amdgcn_mfma_f32_16x16x32_bf16(af, bf, acc[c], 0, 0, 0);
    }
  }

#pragma unroll
  for (int r = 0; r < 4; ++r) {
    int row = row0 + lg * 4 + r;  // m = b*NN + n
    bool ok = row < 40000;
    int b = row / NN;
    int n = row - b * NN;
    size_t dst = ((size_t)n * 4 + b) * 256;  // hs2 row
    float vv[8];
    float pr = 0.f, qr = 0.f;
#pragma unroll
    for (int c = 0; c < 8; ++c) {
      int col = c * 16 + lr;
      float v = acc[c][r] + bt[col];
      v = fmaxf(v, 0.f);
      vv[c] = v;
      if (ok) hs[dst + col] = (__bf16)v;
      pr += v * Wa[col];
      qr += v * Wa[128 + col];
    }
    // fp8 chunk: byte c = col 16c+lr
    int d0 = __builtin_amdgcn_cvt_pk_fp8_f32(vv[0], vv[1], 0, false);
    d0 = __builtin_amdgcn_cvt_pk_fp8_f32(vv[2], vv[3], d0, true);
    int d1 = __builtin_amdgcn_cvt_pk_fp8_f32(vv[4], vv[5], 0, false);
    d1 = __builtin_amdgcn_cvt_pk_fp8_f32(vv[6], vv[7], d1, true);
    if (ok) {
      uint2 st = make_uint2((unsigned)d0, (unsigned)d1);
      *(uint2*)(h8 + ((size_t)n * 4 + b) * 128 + lr * 8) = st;
    }
#pragma unroll
    for (int m = 1; m < 16; m <<= 1) {
      pr += __shfl_xor(pr, m);
      qr += __shfl_xor(qr, m);
    }
    if (lr == 0 && ok) {
      p2[n * 4 + b] = pr;
      q2[n * 4 + b] = qr;
    }
  }
}

// ---------------------------------------------------------------------------
// k_scan: exclusive scan of deg[10000] -> offs, cursor. One block, shfl scan.
__global__ __launch_bounds__(1024) void k_scan(const int* __restrict__ deg,
                                               int* __restrict__ offs,
                                               int* __restrict__ cursor) {
  const int t = threadIdx.x, lane = t & 63, wv = t >> 6;
  const int base = t * 10;
  int local[10];
  int s = 0;
#pragma unroll
  for (int i = 0; i < 10; ++i) {
    int v = (base + i < NN) ? deg[base + i] : 0;
    local[i] = s;
    s += v;
  }
  const int tsum = s;
#pragma unroll
  for (int off = 1; off < 64; off <<= 1) {
    int v = __shfl_up(s, off);
    if (lane >= off) s += v;
  }
  __shared__ int wsum[16];
  if (lane == 63) wsum[wv] = s;
  __syncthreads();
  int add = 0;
#pragma unroll
  for (int w = 0; w < 16; ++w) {
    int v = wsum[w];
    if (w < wv) add += v;
  }
  int pre = add + s - tsum;
#pragma unroll
  for (int i = 0; i < 10; ++i) {
    int idx = base + i;
    if (idx < NN) {
      int o = pre + local[i];
      offs[idx] = o;
      cursor[idx] = o;
    }
  }
  if (t == 1023) offs[NN] = pre + tsum;  // == EE
}

// ---------------------------------------------------------------------------
// k_att: one thread per EDGE. All 4 batches' exp(tanh(...)); claims the CSR
// slot; ONE float4 store (exw) + one int store (tgt); accumulates S.
__global__ __launch_bounds__(256) void k_att(const int* __restrict__ eidx,
                                             const float4* __restrict__ p2,
                                             const float4* __restrict__ q2,
                                             const float* __restrict__ ba,
                                             int* __restrict__ cursor,
                                             int* __restrict__ tgts,
                                             float4* __restrict__ exw,
                                             float* __restrict__ S) {
  int e = blockIdx.x * 256 + threadIdx.x;  // < 160000 exactly
  int s = eidx[2 * e], t = eidx[2 * e + 1];
  float4 pv = p2[s];
  float4 qv = q2[t];
  float bias = ba[0];
#define ATT(pc, qc, out)                              \
  {                                                   \
    float a = (pc) + (qc) + bias;                     \
    float z = __expf(2.f * a);                        \
    float th = 1.f - __fdividef(2.f, z + 1.f);        \
    (out) = __expf(th);                               \
  }
  float v0, v1, v2, v3;
  ATT(pv.x, qv.x, v0)
  ATT(pv.y, qv.y, v1)
  ATT(pv.z, qv.z, v2)
  ATT(pv.w, qv.w, v3)
#undef ATT
  int pos = atomicAdd(&cursor[s], 1);
  tgts[pos] = t;
  exw[pos] = make_float4(v0, v1, v2, v3);
  float vs = v0 + v1 + v2 + v3;
#pragma unroll
  for (int m = 1; m < 64; m <<= 1) vs += __shfl_xor(vs, m);
  __shared__ float part[4];
  int wid = threadIdx.x >> 6, lane = threadIdx.x & 63;
  if (lane == 0) part[wid] = vs;
  __syncthreads();
  if (threadIdx.x == 0) atomicAdd(S, part[0] + part[1] + part[2] + part[3]);
}

// ---------------------------------------------------------------------------
// k_agg: one wave per node. Per edge: ONE 8 B load/lane from the fp8 h copy
// covers all 4 batches (lane = batch myb, chunk sub). acc[c] <-> col 16c+sub;
// the scat-store position sub*8+c is compensated by k_prep's Bcg row remap.
__global__ __launch_bounds__(256) void k_agg(
    const int* __restrict__ tgts, const int* __restrict__ offs,
    const float4* __restrict__ exw, const float* __restrict__ S,
    const char* __restrict__ h8, __bf16* __restrict__ hs) {
  const int wid = threadIdx.x >> 6, lane = threadIdx.x & 63;
  const int n = blockIdx.x * 4 + wid;  // < 10000 exactly (2500 blocks)
  const int myb = lane >> 4, sub = lane & 15;
  const int o0 = offs[n], o1 = offs[n + 1];
  const uint2* __restrict__ h8u = (const uint2*)h8;  // 64 uint2 per node
  float acc[8];
#pragma unroll
  for (int i = 0; i < 8; ++i) acc[i] = 0.f;

  const int lslot = myb * 16 + sub;  // lane's uint2 slot within a node block
  const int wsrc = myb << 4;
  for (int base = o0; base < o1; base += 16) {
    int idx = base + sub;
    bool valid = idx < o1;
    int t_l = valid ? tgts[idx] : 0;
    float4 w4 = valid ? exw[idx] : make_float4(0.f, 0.f, 0.f, 0.f);
    float w_l = (myb == 0) ? w4.x : (myb == 1) ? w4.y : (myb == 2) ? w4.z : w4.w;
    int cnt = min(16, o1 - base);
    for (int j = 0; j < cnt; j += 4) {
      int t0 = __shfl(t_l, j + 0);
      int t1 = __shfl(t_l, j + 1);
      int t2 = __shfl(t_l, j + 2);
      int t3 = __shfl(t_l, j + 3);
      float m0 = __shfl(w_l, wsrc | (j + 0));
      float m1 = __shfl(w_l, wsrc | (j + 1));
      float m2 = __shfl(w_l, wsrc | (j + 2));
      float m3 = __shfl(w_l, wsrc | (j + 3));
      uint2 va = h8u[(size_t)t0 * 64 + lslot];
      uint2 vb = h8u[(size_t)t1 * 64 + lslot];
      uint2 vc = h8u[(size_t)t2 * 64 + lslot];
      uint2 vd = h8u[(size_t)t3 * 64 + lslot];
#define ACC8(m, v)                                                        \
  {                                                                       \
    f32x2 f01 = __builtin_amdgcn_cvt_pk_f32_fp8((int)(v).x, false);       \
    f32x2 f23 = __builtin_amdgcn_cvt_pk_f32_fp8((int)(v).x, true);        \
    f32x2 f45 = __builtin_amdgcn_cvt_pk_f32_fp8((int)(v).y, false);       \
    f32x2 f67 = __builtin_amdgcn_cvt_pk_f32_fp8((int)(v).y, true);        \
    acc[0] = fmaf((m), f01.x, acc[0]); acc[1] = fmaf((m), f01.y, acc[1]); \
    acc[2] = fmaf((m), f23.x, acc[2]); acc[3] = fmaf((m), f23.y, acc[3]); \
    acc[4] = fmaf((m), f45.x, acc[4]); acc[5] = fmaf((m), f45.y, acc[5]); \
    acc[6] = fmaf((m), f67.x, acc[6]); acc[7] = fmaf((m), f67.y, acc[7]); \
  }
      ACC8(m0, va)
      ACC8(m1, vb)
      ACC8(m2, vc)
      ACC8(m3, vd)
#undef ACC8
    }
  }
  const float invS = 1.0f / S[0];
  uint4 st;
  unsigned* sp = (unsigned*)&st;
#pragma unroll
  for (int i = 0; i < 4; ++i) {
    unsigned ux = __float_as_uint(acc[2 * i] * invS);
    ux = (ux + 0x7fffu + ((ux >> 16) & 1u)) >> 16;
    unsigned uy = __float_as_uint(acc[2 * i + 1] * invS);
    uy = (uy + 0x7fffu + ((uy >> 16) & 1u)) >> 16;
    sp[i] = ux | (uy << 16);
  }
  ((uint4*)hs)[(size_t)n * 128 + myb * 32 + 16 + sub] = st;  // scat half
}

// ---------------------------------------------------------------------------
// GEMM2: out = relu(hs2 @ W_c + b_c)  (M=40000 rows m=n*4+b, K=256, N=128)
// 313 blocks x 512 threads; Bcg's K-half row remap matches scat's layout.
__global__ __launch_bounds__(512) void k_gemm_out(
    const __bf16* __restrict__ hs, const __bf16* __restrict__ Bcg,
    const float* __restrict__ bc, float* __restrict__ out) {
  __shared__ __bf16 Bt[64 * 512];  // 64 KB
  const int tid = threadIdx.x;
  {
    uint4* d = (uint4*)Bt;
    const uint4* s = (const uint4*)Bcg;
#pragma unroll
    for (int i = tid; i < 4096; i += 512) d[i] = s[i];
  }
  __syncthreads();

  const int wid = tid >> 6, lane = tid & 63;
  const int lr = lane & 15, lg = lane >> 4;
  const int row0 = blockIdx.x * 128 + wid * 16;

  f32x4 acc[8];
#pragma unroll
  for (int c = 0; c < 8; ++c)
#pragma unroll
    for (int r = 0; r < 4; ++r) acc[c][r] = 0.f;

  const int arow = min(row0 + lr, 39999);  // tail clamp (loads only)

#pragma unroll
  for (int k0 = 0; k0 < 256; k0 += 32) {
    int kk = k0 + lg * 8;
    bf16x8 af = *(const bf16x8*)(hs + (size_t)arow * 256 + kk);
#pragma unroll
    for (int c = 0; c < 8; ++c) {
      bf16x8 bf = *(const bf16x8*)(Bt + (((k0 >> 5) << 3) + c) * 512 + lane * 8);
      acc[c] = __builtin_amdgcn_mfma_f32_16x16x32_bf16(af, bf, acc[c], 0, 0, 0);
    }
  }

#pragma unroll
  for (int r = 0; r < 4; ++r) {
    int m = row0 + lg * 4 + r;  // hs2 row = n*4+b
    if (m < 40000) {
      int n = m >> 2, b = m & 3;
      size_t orow = ((size_t)b * NN + n) * 128;
#pragma unroll
      for (int c = 0; c < 8; ++c) {
        int col = c * 16 + lr;
        float v = acc[c][r] + bc[col];
        out[orow + col] = fmaxf(v, 0.f);
      }
    }
  }
}

// ---------------------------------------------------------------------------
extern "C" void kernel_launch(void* const* d_in, const int* in_sizes, int n_in,
                              void* d_out, int out_size, void* d_ws,
                              size_t ws_size, hipStream_t stream) {
  const float* nf = (const float*)d_in[0];
  const int* eidx = (const int*)d_in[1];
  const float* Wt = (const float*)d_in[2];
  const float* bt = (const float*)d_in[3];
  const float* Wa = (const float*)d_in[4];
  const float* ba = (const float*)d_in[5];
  const float* Wc = (const float*)d_in[6];
  const float* bc = (const float*)d_in[7];
  float* out = (float*)d_out;

  char* w = (char*)d_ws;
  float* S = (float*)(w + WS_S);
  int* deg = (int*)(w + WS_DEG);
  int* offs = (int*)(w + WS_OFFS);
  int* cursor = (int*)(w + WS_CUR);
  int* tgts = (int*)(w + WS_TGT);
  float4* exw = (float4*)(w + WS_EXW);
  float* p2 = (float*)(w + WS_P);
  float* q2 = (float*)(w + WS_Q);
  __bf16* Btg = (__bf16*)(w + WS_BTG);
  __bf16* Bcg = (__bf16*)(w + WS_BCG);
  __bf16* hs = (__bf16*)(w + WS_HS);
  char* h8 = w + WS_H8;

  k_prep<<<8, 256, 0, stream>>>(Wt, Wc, w);
  k_gemm_h<<<313, 512, 0, stream>>>(nf, Btg, bt, Wa, eidx, deg, hs, h8, p2, q2);
  k_scan<<<1, 1024, 0, stream>>>(deg, offs, cursor);
  k_att<<<625, 256, 0, stream>>>(eidx, (const float4*)p2, (const float4*)q2,
                                 ba, cursor, tgts, exw, S);
  k_agg<<<2500, 256, 0, stream>>>(tgts, offs, exw, S, h8, hs);
  k_gemm_out<<<313, 512, 0, stream>>>(hs, Bcg, bc, out);
}